// Round 11
// baseline (112.044 us; speedup 1.0000x reference)
//
#include <hip/hip_runtime.h>

// VQ codebook assign: argmin_k ||x-w_k||^2 = argmax_k (x.w_k - 0.5||w_k||^2)
// Round 11: code-slice waves. Round 10 (codebook in LDS) proved L2-latency;
// remaining 3x gap = per-wave LDS A-frag re-reads (2MB/block) + ds->MFMA
// waits at 2 waves/SIMD. Transpose the mapping: wave w owns a 128-code slice
// with A-frags + bias PINNED IN REGISTERS (loaded once from L2); x B-frags
// staged once in LDS (64KB fp16, frag layout); wave loops over the block's
// 8 point-groups (2-group Bf pipeline). LDS traffic 2MB -> 0.5MB/block; the
// K-loop has no LDS->MFMA dependency at all. Per-point 8-way top-2 union
// merge (slice-ascending = first-occurrence tie rule).
// Exactness: fp16 single-pass + EPS_GAP=1/64 (~5 sigma) + fp64 fixup kernel.
//
// ws: bias[1024]f32 @0 | rec fp16 @4096 (128KB) | cnt @135168 | list @135184

#define BB 32
#define DD 64
#define TT 4096
#define KK 1024
#define EPS_GAP 0.015625f

#define REC_OFF  4096
#define CNT_OFF  135168
#define LIST_OFF 135184

// LDS: xfrag 64KB | s_s1 16KB | s_s2 16KB | s_k1 16KB | s_idx 2KB
#define XF_OFF   0
#define S1_OFF   65536
#define S2_OFF   81920
#define K1_OFF   98304
#define IDX_OFF  114688
#define LDS_BYTES 116736

typedef __attribute__((ext_vector_type(8))) _Float16 half8;
typedef __attribute__((ext_vector_type(4))) float f32x4;

// ---- prep: weight -> swizzled fp16 A-frag records + bias; reset cnt ----
// record r = kc*4 + ks*2 + c (0..127): lane l holds code kc*32+c*16+(l&15),
// d = ks*32+(l>>4)*8+e, 8 halves = 16B. 128 recs * 1KB = 128KB.
__global__ __launch_bounds__(256) void vq_prep(
    const float* __restrict__ w, float* __restrict__ bias,
    _Float16* __restrict__ rec, int* __restrict__ cnt)
{
    const int g    = blockIdx.x * 256 + threadIdx.x;   // 0..8191
    if (g == 0) *cnt = 0;
    const int lane = g & 63;
    const int r    = g >> 6;                           // record 0..127
    const int kc   = r >> 2, ks = (r >> 1) & 1, c = r & 1;
    const int code  = kc * 32 + c * 16 + (lane & 15);
    const int dbase = ks * 32 + (lane >> 4) * 8;

    const float* src = w + (size_t)code * DD + dbase;
    float4 f0 = *(const float4*)src;
    float4 f1 = *(const float4*)(src + 4);
    half8 hv;
    hv[0] = (_Float16)f0.x; hv[1] = (_Float16)f0.y;
    hv[2] = (_Float16)f0.z; hv[3] = (_Float16)f0.w;
    hv[4] = (_Float16)f1.x; hv[5] = (_Float16)f1.y;
    hv[6] = (_Float16)f1.z; hv[7] = (_Float16)f1.w;
    *(half8*)(rec + (size_t)r * 512 + lane * 8) = hv;

    if (g < KK) {
        const float4* wp = (const float4*)(w + (size_t)g * DD);
        float s = 0.f;
        #pragma unroll
        for (int j = 0; j < 16; ++j) {
            float4 v = wp[j];
            s += v.x * v.x + v.y * v.y + v.z * v.z + v.w * v.w;
        }
        bias[g] = -0.5f * s;
    }
}

// ---- main: 8 waves = 8 code-slices; 512 pts/block, 256 blocks ----
__global__ __launch_bounds__(512, 2) void vq_main(
    const float* __restrict__ x,
    const float* __restrict__ weight,
    const float* __restrict__ bias,
    const _Float16* __restrict__ rec,
    int* __restrict__ cnt, int* __restrict__ list, int cap,
    float* __restrict__ out)
{
    extern __shared__ char smem[];
    _Float16* l_xf  = (_Float16*)(smem + XF_OFF);   // [8g][4p][2ks][64lane][8e]
    float*    s_s1  = (float*)(smem + S1_OFF);      // [8 slice][512 pt]
    float*    s_s2  = (float*)(smem + S2_OFF);
    int*      s_k1  = (int*)(smem + K1_OFF);
    int*      s_idx = (int*)(smem + IDX_OFF);

    const int tid  = threadIdx.x;                  // 0..511
    const int lane = tid & 63;
    const int wv   = tid >> 6;                     // 0..7 = code-slice AND stage-group
    const int bb   = blockIdx.x >> 3;              // 8 tiles of 512 pts per batch
    const int t0   = (blockIdx.x & 7) << 9;
    const int col  = lane & 15, kg = lane >> 4;

    // ---- A-slice + bias into REGISTERS (this wave's 4 chunks = 128 codes) ----
    half8 Areg[4][2][2];                           // [cp][ks][c]
    f32x4 Breg[4][2];                              // [cp][c]
    #pragma unroll
    for (int cp = 0; cp < 4; ++cp) {
        const int kc = wv * 4 + cp;
        #pragma unroll
        for (int ks = 0; ks < 2; ++ks)
            #pragma unroll
            for (int c = 0; c < 2; ++c)
                Areg[cp][ks][c] = *(const half8*)(rec + (size_t)(kc * 4 + ks * 2 + c) * 512 + lane * 8);
        #pragma unroll
        for (int c = 0; c < 2; ++c)
            Breg[cp][c] = *(const f32x4*)(bias + kc * 32 + c * 16 + kg * 4);
    }

    // ---- stage x group wv -> LDS B-frags (fp16, frag layout) ----
    {
        const float* xb = x + (size_t)bb * DD * TT + t0 + wv * 64 + col;
        #pragma unroll
        for (int p = 0; p < 4; ++p)
            #pragma unroll
            for (int ks = 0; ks < 2; ++ks) {
                half8 hv;
                #pragma unroll
                for (int e = 0; e < 8; ++e)
                    hv[e] = (_Float16)xb[(size_t)(ks * 32 + kg * 8 + e) * TT + p * 16];
                *(half8*)(l_xf + ((wv * 4 + p) * 2 + ks) * 512 + lane * 8) = hv;
            }
    }
    __syncthreads();

    // ---- loop over 8 point-groups, 2-group Bf pipeline ----
    auto loadBf = [&](int g, half8 (*B)[2]) {
        #pragma unroll
        for (int p = 0; p < 4; ++p)
            #pragma unroll
            for (int ks = 0; ks < 2; ++ks)
                B[p][ks] = *(const half8*)(l_xf + ((g * 4 + p) * 2 + ks) * 512 + lane * 8);
    };

    half8 BfA[4][2], BfB[4][2];
    loadBf(0, BfA);
    #pragma unroll
    for (int g = 0; g < 8; ++g) {
        half8 (*Bc)[2] = (g & 1) ? BfB : BfA;
        half8 (*Bn)[2] = (g & 1) ? BfA : BfB;
        if (g + 1 < 8) loadBf(g + 1, Bn);

        float s1[4] = {-1e30f, -1e30f, -1e30f, -1e30f};
        float s2[4] = {-1e30f, -1e30f, -1e30f, -1e30f};
        int   k1[4] = {0, 0, 0, 0};

        #pragma unroll
        for (int cp = 0; cp < 4; ++cp) {
            f32x4 acc[2][4];                       // [c-tile][pt-tile]
            #pragma unroll
            for (int c = 0; c < 2; ++c)
                #pragma unroll
                for (int p = 0; p < 4; ++p) {
                    acc[c][p] = __builtin_amdgcn_mfma_f32_16x16x32_f16(Areg[cp][0][c], Bc[p][0], Breg[cp][c], 0, 0, 0);
                    acc[c][p] = __builtin_amdgcn_mfma_f32_16x16x32_f16(Areg[cp][1][c], Bc[p][1], acc[c][p], 0, 0, 0);
                }
            #pragma unroll
            for (int p = 0; p < 4; ++p)
                #pragma unroll
                for (int c = 0; c < 2; ++c)
                    #pragma unroll
                    for (int r = 0; r < 4; ++r) {
                        const float s = acc[c][p][r];
                        const int code = (wv * 4 + cp) * 32 + c * 16 + kg * 4 + r;
                        const float ns2 = __builtin_amdgcn_fmed3f(s, s1[p], s2[p]);
                        if (s > s1[p]) { k1[p] = code; s1[p] = s; }
                        s2[p] = ns2;
                    }
        }

        // intra-wave merge: lanes l, l^16, l^32, l^48 share a point
        #pragma unroll
        for (int p = 0; p < 4; ++p) {
            #pragma unroll
            for (int off = 16; off < 64; off <<= 1) {
                float o1 = __shfl_xor(s1[p], off, 64);
                float o2 = __shfl_xor(s2[p], off, 64);
                int   ok = __shfl_xor(k1[p], off, 64);
                bool takeo = (o1 > s1[p]) || (o1 == s1[p] && ok < k1[p]);
                float ns2 = fmaxf(fminf(s1[p], o1), fmaxf(s2[p], o2));
                if (takeo) { s1[p] = o1; k1[p] = ok; }
                s2[p] = ns2;
            }
            if (lane < 16) {
                const int pt = g * 64 + p * 16 + lane;
                s_s1[wv * 512 + pt] = s1[p];
                s_s2[wv * 512 + pt] = s2[p];
                s_k1[wv * 512 + pt] = k1[p];
            }
        }
    }
    __syncthreads();

    // ---- per-point 8-way union-top2 merge (thread = pt) ----
    {
        const int pt = tid;
        float m1 = s_s1[pt], m2 = s_s2[pt];
        int   mk = s_k1[pt];
        #pragma unroll
        for (int w = 1; w < 8; ++w) {
            const float a1 = s_s1[w * 512 + pt];
            const float a2 = s_s2[w * 512 + pt];
            const int   ak = s_k1[w * 512 + pt];
            // strict >: ascending slices = ascending codes -> first-occurrence
            if (a1 > m1) { m2 = fmaxf(m1, a2); m1 = a1; mk = ak; }
            else         { m2 = fmaxf(m2, a1); }
        }
        s_idx[pt] = mk;

        // near-tie: batched push to worklist (one atomic per wave)
        const bool flag = (m1 - m2) <= EPS_GAP;
        unsigned long long m = __ballot(flag);
        if (m) {
            int base = 0;
            if (lane == 0) base = atomicAdd(cnt, __popcll(m));
            base = __shfl(base, 0, 64);
            if (flag) {
                const int my = base + __popcll(m & ((1ull << lane) - 1));
                if (my < cap) {
                    list[my] = bb * TT + t0 + pt;
                } else {
                    // overflow fallback: exact fp64 scan (never in practice)
                    const float* xp = x + (size_t)bb * DD * TT + t0 + pt;
                    double bd = 1e300; int bk2 = 0;
                    for (int k = 0; k < KK; ++k) {
                        const float* wk = weight + (size_t)k * DD;
                        double a0 = 0.0;
                        for (int d = 0; d < DD; ++d) {
                            double e = (double)xp[(size_t)d * TT] - (double)wk[d];
                            a0 = fma(e, e, a0);
                        }
                        if (a0 < bd) { bd = a0; bk2 = k; }
                    }
                    s_idx[pt] = bk2;
                }
            }
        }
    }
    __syncthreads();

    // ---- epilogue: 512-pt tiles -> 2KB contiguous regions per (b,d) ----
    out[(size_t)BB * DD * TT + (size_t)bb * TT + t0 + tid] = (float)s_idx[tid];

    {
        const int kq = s_idx[tid];
        const float4* wr = (const float4*)(weight + (size_t)kq * DD);
        float* op = out + (size_t)bb * DD * TT + t0 + tid;
        #pragma unroll
        for (int jq = 0; jq < 16; ++jq) {
            float4 v = wr[jq];
            op[(size_t)(jq * 4 + 0) * TT] = v.x;
            op[(size_t)(jq * 4 + 1) * TT] = v.y;
            op[(size_t)(jq * 4 + 2) * TT] = v.z;
            op[(size_t)(jq * 4 + 3) * TT] = v.w;
        }
    }
}

// ---- fixup: flagged points, coalesced exact fp64 full scan ----
__global__ __launch_bounds__(256) void vq_fixup(
    const float* __restrict__ x, const float* __restrict__ w,
    const int* __restrict__ cnt, const int* __restrict__ list, int cap,
    float* __restrict__ out)
{
    __shared__ double sd[4];
    __shared__ int    sk[4];
    int n = *cnt; if (n > cap) n = cap;

    for (int i = blockIdx.x; i < n; i += gridDim.x) {
        const int g = list[i];
        const int b = g >> 12;             // TT = 4096
        const int t = g & (TT - 1);
        const float* xp = x + (size_t)b * DD * TT + t;

        const int quarter = threadIdx.x & 3;       // 16 d's each
        const int cbase   = threadIdx.x >> 2;      // 0..63

        double xq[16];
        #pragma unroll
        for (int j = 0; j < 16; ++j)
            xq[j] = (double)xp[(size_t)(quarter * 16 + j) * TT];

        double bd = 1e300; int bk = 0;
        for (int it = 0; it < 16; ++it) {
            const int code = cbase + (it << 6);
            const float4* wr = (const float4*)(w + (size_t)code * DD + quarter * 16);
            double a = 0.0;
            #pragma unroll
            for (int q4 = 0; q4 < 4; ++q4) {
                float4 v = wr[q4];
                double e0 = xq[q4 * 4 + 0] - (double)v.x;
                double e1 = xq[q4 * 4 + 1] - (double)v.y;
                double e2 = xq[q4 * 4 + 2] - (double)v.z;
                double e3 = xq[q4 * 4 + 3] - (double)v.w;
                a = fma(e0, e0, a); a = fma(e1, e1, a);
                a = fma(e2, e2, a); a = fma(e3, e3, a);
            }
            a += __shfl_xor(a, 1, 64);
            a += __shfl_xor(a, 2, 64);
            if (a < bd || (a == bd && code < bk)) { bd = a; bk = code; }
        }
        #pragma unroll
        for (int off = 4; off < 64; off <<= 1) {
            double od = __shfl_xor(bd, off, 64);
            int    ok = __shfl_xor(bk, off, 64);
            if (od < bd || (od == bd && ok < bk)) { bd = od; bk = ok; }
        }
        if ((threadIdx.x & 63) == 0) { sd[threadIdx.x >> 6] = bd; sk[threadIdx.x >> 6] = bk; }
        __syncthreads();
        double fb = sd[0]; int fk = sk[0];
        #pragma unroll
        for (int wvi = 1; wvi < 4; ++wvi)
            if (sd[wvi] < fb || (sd[wvi] == fb && sk[wvi] < fk)) { fb = sd[wvi]; fk = sk[wvi]; }

        if (threadIdx.x == 0)
            out[(size_t)BB * DD * TT + g] = (float)fk;
        if (threadIdx.x < 64)
            out[(size_t)b * DD * TT + (size_t)threadIdx.x * TT + t] = w[(size_t)fk * DD + threadIdx.x];
        __syncthreads();   // sd/sk reuse across iterations
    }
}

extern "C" void kernel_launch(void* const* d_in, const int* in_sizes, int n_in,
                              void* d_out, int out_size, void* d_ws, size_t ws_size,
                              hipStream_t stream) {
    const float* x      = (const float*)d_in[0];
    const float* weight = (const float*)d_in[1];
    float* out = (float*)d_out;

    float* bias     = (float*)d_ws;
    _Float16* rec   = (_Float16*)((char*)d_ws + REC_OFF);
    int* cnt        = (int*)((char*)d_ws + CNT_OFF);
    int* list       = (int*)((char*)d_ws + LIST_OFF);
    long long avail = (long long)ws_size - LIST_OFF;
    int cap = avail > 0 ? (int)(avail / 4) : 0;
    if (cap > BB * TT) cap = BB * TT;

    vq_prep<<<32, 256, 0, stream>>>(weight, bias, rec, cnt);
    vq_main<<<(BB * TT) / 512, 512, LDS_BYTES, stream>>>(x, weight, bias, rec, cnt, list, cap, out);
    vq_fixup<<<1024, 256, 0, stream>>>(x, weight, cnt, list, cap, out);
}

// Round 12
// 99.016 us; speedup vs baseline: 1.1316x; 1.1316x over previous
//
#include <hip/hip_runtime.h>

// VQ codebook assign: argmin_k ||x-w_k||^2 = argmax_k (x.w_k - 0.5||w_k||^2)
// Round 12: round-11 structure (code-slice waves, A-frags+bias pinned in
// registers, x B-frags staged once in LDS) with the REGISTER BUDGET FIXED.
// Round 11's __launch_bounds__(512,2) capped VGPR at 128 vs ~210 needed ->
// scratch spills -> FETCH_SIZE 193MB. Fix: __launch_bounds__(512) (cap 256)
// + single Bf buffer (~185 VGPR live). Wave w owns codes [128w,128w+128);
// loops over 8 point-groups from LDS; per-point 8-way union-top2 merge.
// Exactness: fp16 single-pass + EPS_GAP=1/64 (~5 sigma) + fp64 fixup kernel.
//
// ws: bias[1024]f32 @0 | rec fp16 @4096 (128KB) | cnt @135168 | list @135184

#define BB 32
#define DD 64
#define TT 4096
#define KK 1024
#define EPS_GAP 0.015625f

#define REC_OFF  4096
#define CNT_OFF  135168
#define LIST_OFF 135184

// LDS: xfrag 64KB | s_s1 16KB | s_s2 16KB | s_k1 16KB | s_idx 2KB
#define XF_OFF   0
#define S1_OFF   65536
#define S2_OFF   81920
#define K1_OFF   98304
#define IDX_OFF  114688
#define LDS_BYTES 116736

typedef __attribute__((ext_vector_type(8))) _Float16 half8;
typedef __attribute__((ext_vector_type(4))) float f32x4;

// ---- prep: weight -> swizzled fp16 A-frag records + bias; reset cnt ----
// record r = kc*4 + ks*2 + c (0..127): lane l holds code kc*32+c*16+(l&15),
// d = ks*32+(l>>4)*8+e, 8 halves = 16B. 128 recs * 1KB = 128KB.
__global__ __launch_bounds__(256) void vq_prep(
    const float* __restrict__ w, float* __restrict__ bias,
    _Float16* __restrict__ rec, int* __restrict__ cnt)
{
    const int g    = blockIdx.x * 256 + threadIdx.x;   // 0..8191
    if (g == 0) *cnt = 0;
    const int lane = g & 63;
    const int r    = g >> 6;                           // record 0..127
    const int kc   = r >> 2, ks = (r >> 1) & 1, c = r & 1;
    const int code  = kc * 32 + c * 16 + (lane & 15);
    const int dbase = ks * 32 + (lane >> 4) * 8;

    const float* src = w + (size_t)code * DD + dbase;
    float4 f0 = *(const float4*)src;
    float4 f1 = *(const float4*)(src + 4);
    half8 hv;
    hv[0] = (_Float16)f0.x; hv[1] = (_Float16)f0.y;
    hv[2] = (_Float16)f0.z; hv[3] = (_Float16)f0.w;
    hv[4] = (_Float16)f1.x; hv[5] = (_Float16)f1.y;
    hv[6] = (_Float16)f1.z; hv[7] = (_Float16)f1.w;
    *(half8*)(rec + (size_t)r * 512 + lane * 8) = hv;

    if (g < KK) {
        const float4* wp = (const float4*)(w + (size_t)g * DD);
        float s = 0.f;
        #pragma unroll
        for (int j = 0; j < 16; ++j) {
            float4 v = wp[j];
            s += v.x * v.x + v.y * v.y + v.z * v.z + v.w * v.w;
        }
        bias[g] = -0.5f * s;
    }
}

// ---- main: 8 waves = 8 code-slices; 512 pts/block, 256 blocks ----
__global__ __launch_bounds__(512) void vq_main(
    const float* __restrict__ x,
    const float* __restrict__ weight,
    const float* __restrict__ bias,
    const _Float16* __restrict__ rec,
    int* __restrict__ cnt, int* __restrict__ list, int cap,
    float* __restrict__ out)
{
    extern __shared__ char smem[];
    _Float16* l_xf  = (_Float16*)(smem + XF_OFF);   // [8g][4p][2ks][64lane][8e]
    float*    s_s1  = (float*)(smem + S1_OFF);      // [8 slice][512 pt]
    float*    s_s2  = (float*)(smem + S2_OFF);
    int*      s_k1  = (int*)(smem + K1_OFF);
    int*      s_idx = (int*)(smem + IDX_OFF);

    const int tid  = threadIdx.x;                  // 0..511
    const int lane = tid & 63;
    const int wv   = tid >> 6;                     // 0..7 = code-slice AND stage-group
    const int bb   = blockIdx.x >> 3;              // 8 tiles of 512 pts per batch
    const int t0   = (blockIdx.x & 7) << 9;
    const int col  = lane & 15, kg = lane >> 4;

    // ---- A-slice + bias into REGISTERS (this wave's 4 chunks = 128 codes) ----
    half8 Areg[4][2][2];                           // [cp][ks][c] = 64 VGPR
    f32x4 Breg[4][2];                              // [cp][c]     = 32 VGPR
    #pragma unroll
    for (int cp = 0; cp < 4; ++cp) {
        const int kc = wv * 4 + cp;
        #pragma unroll
        for (int ks = 0; ks < 2; ++ks)
            #pragma unroll
            for (int c = 0; c < 2; ++c)
                Areg[cp][ks][c] = *(const half8*)(rec + (size_t)(kc * 4 + ks * 2 + c) * 512 + lane * 8);
        #pragma unroll
        for (int c = 0; c < 2; ++c)
            Breg[cp][c] = *(const f32x4*)(bias + kc * 32 + c * 16 + kg * 4);
    }

    // ---- stage x group wv -> LDS B-frags (fp16, frag layout) ----
    {
        const float* xb = x + (size_t)bb * DD * TT + t0 + wv * 64 + col;
        #pragma unroll
        for (int p = 0; p < 4; ++p)
            #pragma unroll
            for (int ks = 0; ks < 2; ++ks) {
                half8 hv;
                #pragma unroll
                for (int e = 0; e < 8; ++e)
                    hv[e] = (_Float16)xb[(size_t)(ks * 32 + kg * 8 + e) * TT + p * 16];
                *(half8*)(l_xf + ((wv * 4 + p) * 2 + ks) * 512 + lane * 8) = hv;
            }
    }
    __syncthreads();

    // ---- loop over 8 point-groups (single Bf buffer; ds->MFMA covered by
    //      the co-resident wave at 2 waves/SIMD) ----
    for (int g = 0; g < 8; ++g) {
        half8 Bf[4][2];
        #pragma unroll
        for (int p = 0; p < 4; ++p)
            #pragma unroll
            for (int ks = 0; ks < 2; ++ks)
                Bf[p][ks] = *(const half8*)(l_xf + ((g * 4 + p) * 2 + ks) * 512 + lane * 8);

        float s1[4] = {-1e30f, -1e30f, -1e30f, -1e30f};
        float s2[4] = {-1e30f, -1e30f, -1e30f, -1e30f};
        int   k1[4] = {0, 0, 0, 0};

        #pragma unroll
        for (int cp = 0; cp < 4; ++cp) {
            f32x4 acc[2][4];                       // [c-tile][pt-tile] = 32 VGPR
            #pragma unroll
            for (int c = 0; c < 2; ++c)
                #pragma unroll
                for (int p = 0; p < 4; ++p) {
                    acc[c][p] = __builtin_amdgcn_mfma_f32_16x16x32_f16(Areg[cp][0][c], Bf[p][0], Breg[cp][c], 0, 0, 0);
                    acc[c][p] = __builtin_amdgcn_mfma_f32_16x16x32_f16(Areg[cp][1][c], Bf[p][1], acc[c][p], 0, 0, 0);
                }
            #pragma unroll
            for (int p = 0; p < 4; ++p)
                #pragma unroll
                for (int c = 0; c < 2; ++c)
                    #pragma unroll
                    for (int r = 0; r < 4; ++r) {
                        const float s = acc[c][p][r];
                        const int code = (wv * 4 + cp) * 32 + c * 16 + kg * 4 + r;
                        const float ns2 = __builtin_amdgcn_fmed3f(s, s1[p], s2[p]);
                        if (s > s1[p]) { k1[p] = code; s1[p] = s; }
                        s2[p] = ns2;
                    }
        }

        // intra-wave merge: lanes l, l^16, l^32, l^48 share a point
        #pragma unroll
        for (int p = 0; p < 4; ++p) {
            #pragma unroll
            for (int off = 16; off < 64; off <<= 1) {
                float o1 = __shfl_xor(s1[p], off, 64);
                float o2 = __shfl_xor(s2[p], off, 64);
                int   ok = __shfl_xor(k1[p], off, 64);
                bool takeo = (o1 > s1[p]) || (o1 == s1[p] && ok < k1[p]);
                float ns2 = fmaxf(fminf(s1[p], o1), fmaxf(s2[p], o2));
                if (takeo) { s1[p] = o1; k1[p] = ok; }
                s2[p] = ns2;
            }
            if (lane < 16) {
                const int pt = g * 64 + p * 16 + lane;
                s_s1[wv * 512 + pt] = s1[p];
                s_s2[wv * 512 + pt] = s2[p];
                s_k1[wv * 512 + pt] = k1[p];
            }
        }
    }
    __syncthreads();

    // ---- per-point 8-way union-top2 merge (thread = pt) ----
    {
        const int pt = tid;
        float m1 = s_s1[pt], m2 = s_s2[pt];
        int   mk = s_k1[pt];
        #pragma unroll
        for (int w = 1; w < 8; ++w) {
            const float a1 = s_s1[w * 512 + pt];
            const float a2 = s_s2[w * 512 + pt];
            const int   ak = s_k1[w * 512 + pt];
            // strict >: ascending slices = ascending codes -> first-occurrence
            if (a1 > m1) { m2 = fmaxf(m1, a2); m1 = a1; mk = ak; }
            else         { m2 = fmaxf(m2, a1); }
        }
        s_idx[pt] = mk;

        // near-tie: batched push to worklist (one atomic per wave)
        const bool flag = (m1 - m2) <= EPS_GAP;
        unsigned long long m = __ballot(flag);
        if (m) {
            int base = 0;
            if (lane == 0) base = atomicAdd(cnt, __popcll(m));
            base = __shfl(base, 0, 64);
            if (flag) {
                const int my = base + __popcll(m & ((1ull << lane) - 1));
                if (my < cap) {
                    list[my] = bb * TT + t0 + pt;
                } else {
                    // overflow fallback: exact fp64 scan (never in practice)
                    const float* xp = x + (size_t)bb * DD * TT + t0 + pt;
                    double bd = 1e300; int bk2 = 0;
                    for (int k = 0; k < KK; ++k) {
                        const float* wk = weight + (size_t)k * DD;
                        double a0 = 0.0;
                        for (int d = 0; d < DD; ++d) {
                            double e = (double)xp[(size_t)d * TT] - (double)wk[d];
                            a0 = fma(e, e, a0);
                        }
                        if (a0 < bd) { bd = a0; bk2 = k; }
                    }
                    s_idx[pt] = bk2;
                }
            }
        }
    }
    __syncthreads();

    // ---- epilogue: 512-pt tiles -> 2KB contiguous regions per (b,d) ----
    out[(size_t)BB * DD * TT + (size_t)bb * TT + t0 + tid] = (float)s_idx[tid];

    {
        const int kq = s_idx[tid];
        const float4* wr = (const float4*)(weight + (size_t)kq * DD);
        float* op = out + (size_t)bb * DD * TT + t0 + tid;
        #pragma unroll
        for (int jq = 0; jq < 16; ++jq) {
            float4 v = wr[jq];
            op[(size_t)(jq * 4 + 0) * TT] = v.x;
            op[(size_t)(jq * 4 + 1) * TT] = v.y;
            op[(size_t)(jq * 4 + 2) * TT] = v.z;
            op[(size_t)(jq * 4 + 3) * TT] = v.w;
        }
    }
}

// ---- fixup: flagged points, coalesced exact fp64 full scan ----
__global__ __launch_bounds__(256) void vq_fixup(
    const float* __restrict__ x, const float* __restrict__ w,
    const int* __restrict__ cnt, const int* __restrict__ list, int cap,
    float* __restrict__ out)
{
    __shared__ double sd[4];
    __shared__ int    sk[4];
    int n = *cnt; if (n > cap) n = cap;

    for (int i = blockIdx.x; i < n; i += gridDim.x) {
        const int g = list[i];
        const int b = g >> 12;             // TT = 4096
        const int t = g & (TT - 1);
        const float* xp = x + (size_t)b * DD * TT + t;

        const int quarter = threadIdx.x & 3;       // 16 d's each
        const int cbase   = threadIdx.x >> 2;      // 0..63

        double xq[16];
        #pragma unroll
        for (int j = 0; j < 16; ++j)
            xq[j] = (double)xp[(size_t)(quarter * 16 + j) * TT];

        double bd = 1e300; int bk = 0;
        for (int it = 0; it < 16; ++it) {
            const int code = cbase + (it << 6);
            const float4* wr = (const float4*)(w + (size_t)code * DD + quarter * 16);
            double a = 0.0;
            #pragma unroll
            for (int q4 = 0; q4 < 4; ++q4) {
                float4 v = wr[q4];
                double e0 = xq[q4 * 4 + 0] - (double)v.x;
                double e1 = xq[q4 * 4 + 1] - (double)v.y;
                double e2 = xq[q4 * 4 + 2] - (double)v.z;
                double e3 = xq[q4 * 4 + 3] - (double)v.w;
                a = fma(e0, e0, a); a = fma(e1, e1, a);
                a = fma(e2, e2, a); a = fma(e3, e3, a);
            }
            a += __shfl_xor(a, 1, 64);
            a += __shfl_xor(a, 2, 64);
            if (a < bd || (a == bd && code < bk)) { bd = a; bk = code; }
        }
        #pragma unroll
        for (int off = 4; off < 64; off <<= 1) {
            double od = __shfl_xor(bd, off, 64);
            int    ok = __shfl_xor(bk, off, 64);
            if (od < bd || (od == bd && ok < bk)) { bd = od; bk = ok; }
        }
        if ((threadIdx.x & 63) == 0) { sd[threadIdx.x >> 6] = bd; sk[threadIdx.x >> 6] = bk; }
        __syncthreads();
        double fb = sd[0]; int fk = sk[0];
        #pragma unroll
        for (int wvi = 1; wvi < 4; ++wvi)
            if (sd[wvi] < fb || (sd[wvi] == fb && sk[wvi] < fk)) { fb = sd[wvi]; fk = sk[wvi]; }

        if (threadIdx.x == 0)
            out[(size_t)BB * DD * TT + g] = (float)fk;
        if (threadIdx.x < 64)
            out[(size_t)b * DD * TT + (size_t)threadIdx.x * TT + t] = w[(size_t)fk * DD + threadIdx.x];
        __syncthreads();   // sd/sk reuse across iterations
    }
}

extern "C" void kernel_launch(void* const* d_in, const int* in_sizes, int n_in,
                              void* d_out, int out_size, void* d_ws, size_t ws_size,
                              hipStream_t stream) {
    const float* x      = (const float*)d_in[0];
    const float* weight = (const float*)d_in[1];
    float* out = (float*)d_out;

    float* bias     = (float*)d_ws;
    _Float16* rec   = (_Float16*)((char*)d_ws + REC_OFF);
    int* cnt        = (int*)((char*)d_ws + CNT_OFF);
    int* list       = (int*)((char*)d_ws + LIST_OFF);
    long long avail = (long long)ws_size - LIST_OFF;
    int cap = avail > 0 ? (int)(avail / 4) : 0;
    if (cap > BB * TT) cap = BB * TT;

    vq_prep<<<32, 256, 0, stream>>>(weight, bias, rec, cnt);
    vq_main<<<(BB * TT) / 512, 512, LDS_BYTES, stream>>>(x, weight, bias, rec, cnt, list, cap, out);
    vq_fixup<<<1024, 256, 0, stream>>>(x, weight, cnt, list, cap, out);
}

// Round 13
// 98.717 us; speedup vs baseline: 1.1350x; 1.0030x over previous
//
#include <hip/hip_runtime.h>

// VQ codebook assign: argmin_k ||x-w_k||^2 = argmax_k (x.w_k - 0.5||w_k||^2)
// Round 13: round-12 structure with the register cap ACTUALLY lifted.
// Rounds 11/12 spilled because launch_bounds (512,2)/(512) cap VGPR at 128
// (dynamic LDS hides the occupancy cap from the compiler heuristic);
// round 10 proved (512,1) lets the allocator use what the kernel needs.
// Live state ~190 VGPR < 256 cap (8-wave block => 2 waves/SIMD).
// Wave w owns codes [128w,128w+128) with A-frags+bias pinned in registers;
// x B-frags staged once in LDS; wave loops over 8 point-groups; per-point
// 8-way union-top2 merge; worklist + fp64 fixup for near-ties (EPS=1/64).
//
// ws: bias[1024]f32 @0 | rec fp16 @4096 (128KB) | cnt @135168 | list @135184

#define BB 32
#define DD 64
#define TT 4096
#define KK 1024
#define EPS_GAP 0.015625f

#define REC_OFF  4096
#define CNT_OFF  135168
#define LIST_OFF 135184

// LDS: xfrag 64KB | s_s1 16KB | s_s2 16KB | s_k1 16KB | s_idx 2KB
#define XF_OFF   0
#define S1_OFF   65536
#define S2_OFF   81920
#define K1_OFF   98304
#define IDX_OFF  114688
#define LDS_BYTES 116736

typedef __attribute__((ext_vector_type(8))) _Float16 half8;
typedef __attribute__((ext_vector_type(4))) float f32x4;

// ---- prep: weight -> swizzled fp16 A-frag records + bias; reset cnt ----
// record r = kc*4 + ks*2 + c (0..127): lane l holds code kc*32+c*16+(l&15),
// d = ks*32+(l>>4)*8+e, 8 halves = 16B. 128 recs * 1KB = 128KB.
__global__ __launch_bounds__(256) void vq_prep(
    const float* __restrict__ w, float* __restrict__ bias,
    _Float16* __restrict__ rec, int* __restrict__ cnt)
{
    const int g    = blockIdx.x * 256 + threadIdx.x;   // 0..8191
    if (g == 0) *cnt = 0;
    const int lane = g & 63;
    const int r    = g >> 6;                           // record 0..127
    const int kc   = r >> 2, ks = (r >> 1) & 1, c = r & 1;
    const int code  = kc * 32 + c * 16 + (lane & 15);
    const int dbase = ks * 32 + (lane >> 4) * 8;

    const float* src = w + (size_t)code * DD + dbase;
    float4 f0 = *(const float4*)src;
    float4 f1 = *(const float4*)(src + 4);
    half8 hv;
    hv[0] = (_Float16)f0.x; hv[1] = (_Float16)f0.y;
    hv[2] = (_Float16)f0.z; hv[3] = (_Float16)f0.w;
    hv[4] = (_Float16)f1.x; hv[5] = (_Float16)f1.y;
    hv[6] = (_Float16)f1.z; hv[7] = (_Float16)f1.w;
    *(half8*)(rec + (size_t)r * 512 + lane * 8) = hv;

    if (g < KK) {
        const float4* wp = (const float4*)(w + (size_t)g * DD);
        float s = 0.f;
        #pragma unroll
        for (int j = 0; j < 16; ++j) {
            float4 v = wp[j];
            s += v.x * v.x + v.y * v.y + v.z * v.z + v.w * v.w;
        }
        bias[g] = -0.5f * s;
    }
}

// ---- main: 8 waves = 8 code-slices; 512 pts/block, 256 blocks ----
__global__ __launch_bounds__(512, 1) void vq_main(
    const float* __restrict__ x,
    const float* __restrict__ weight,
    const float* __restrict__ bias,
    const _Float16* __restrict__ rec,
    int* __restrict__ cnt, int* __restrict__ list, int cap,
    float* __restrict__ out)
{
    extern __shared__ char smem[];
    _Float16* l_xf  = (_Float16*)(smem + XF_OFF);   // [8g][4p][2ks][64lane][8e]
    float*    s_s1  = (float*)(smem + S1_OFF);      // [8 slice][512 pt]
    float*    s_s2  = (float*)(smem + S2_OFF);
    int*      s_k1  = (int*)(smem + K1_OFF);
    int*      s_idx = (int*)(smem + IDX_OFF);

    const int tid  = threadIdx.x;                  // 0..511
    const int lane = tid & 63;
    const int wv   = tid >> 6;                     // 0..7 = code-slice AND stage-group
    const int bb   = blockIdx.x >> 3;              // 8 tiles of 512 pts per batch
    const int t0   = (blockIdx.x & 7) << 9;
    const int col  = lane & 15, kg = lane >> 4;

    // ---- A-slice + bias into REGISTERS (this wave's 4 chunks = 128 codes) ----
    half8 Areg[4][2][2];                           // [cp][ks][c] = 64 VGPR
    f32x4 Breg[4][2];                              // [cp][c]     = 32 VGPR
    #pragma unroll
    for (int cp = 0; cp < 4; ++cp) {
        const int kc = wv * 4 + cp;
        #pragma unroll
        for (int ks = 0; ks < 2; ++ks)
            #pragma unroll
            for (int c = 0; c < 2; ++c)
                Areg[cp][ks][c] = *(const half8*)(rec + (size_t)(kc * 4 + ks * 2 + c) * 512 + lane * 8);
        #pragma unroll
        for (int c = 0; c < 2; ++c)
            Breg[cp][c] = *(const f32x4*)(bias + kc * 32 + c * 16 + kg * 4);
    }

    // ---- stage x group wv -> LDS B-frags (fp16, frag layout) ----
    {
        const float* xb = x + (size_t)bb * DD * TT + t0 + wv * 64 + col;
        #pragma unroll
        for (int p = 0; p < 4; ++p)
            #pragma unroll
            for (int ks = 0; ks < 2; ++ks) {
                half8 hv;
                #pragma unroll
                for (int e = 0; e < 8; ++e)
                    hv[e] = (_Float16)xb[(size_t)(ks * 32 + kg * 8 + e) * TT + p * 16];
                *(half8*)(l_xf + ((wv * 4 + p) * 2 + ks) * 512 + lane * 8) = hv;
            }
    }
    __syncthreads();

    // ---- loop over 8 point-groups (single Bf buffer; ds->MFMA covered by
    //      the co-resident wave at 2 waves/SIMD) ----
    for (int g = 0; g < 8; ++g) {
        half8 Bf[4][2];
        #pragma unroll
        for (int p = 0; p < 4; ++p)
            #pragma unroll
            for (int ks = 0; ks < 2; ++ks)
                Bf[p][ks] = *(const half8*)(l_xf + ((g * 4 + p) * 2 + ks) * 512 + lane * 8);

        float s1[4] = {-1e30f, -1e30f, -1e30f, -1e30f};
        float s2[4] = {-1e30f, -1e30f, -1e30f, -1e30f};
        int   k1[4] = {0, 0, 0, 0};

        #pragma unroll
        for (int cp = 0; cp < 4; ++cp) {
            f32x4 acc[2][4];                       // [c-tile][pt-tile] = 32 VGPR
            #pragma unroll
            for (int c = 0; c < 2; ++c)
                #pragma unroll
                for (int p = 0; p < 4; ++p) {
                    acc[c][p] = __builtin_amdgcn_mfma_f32_16x16x32_f16(Areg[cp][0][c], Bf[p][0], Breg[cp][c], 0, 0, 0);
                    acc[c][p] = __builtin_amdgcn_mfma_f32_16x16x32_f16(Areg[cp][1][c], Bf[p][1], acc[c][p], 0, 0, 0);
                }
            #pragma unroll
            for (int p = 0; p < 4; ++p)
                #pragma unroll
                for (int c = 0; c < 2; ++c)
                    #pragma unroll
                    for (int r = 0; r < 4; ++r) {
                        const float s = acc[c][p][r];
                        const int code = (wv * 4 + cp) * 32 + c * 16 + kg * 4 + r;
                        const float ns2 = __builtin_amdgcn_fmed3f(s, s1[p], s2[p]);
                        if (s > s1[p]) { k1[p] = code; s1[p] = s; }
                        s2[p] = ns2;
                    }
        }

        // intra-wave merge: lanes l, l^16, l^32, l^48 share a point
        #pragma unroll
        for (int p = 0; p < 4; ++p) {
            #pragma unroll
            for (int off = 16; off < 64; off <<= 1) {
                float o1 = __shfl_xor(s1[p], off, 64);
                float o2 = __shfl_xor(s2[p], off, 64);
                int   ok = __shfl_xor(k1[p], off, 64);
                bool takeo = (o1 > s1[p]) || (o1 == s1[p] && ok < k1[p]);
                float ns2 = fmaxf(fminf(s1[p], o1), fmaxf(s2[p], o2));
                if (takeo) { s1[p] = o1; k1[p] = ok; }
                s2[p] = ns2;
            }
            if (lane < 16) {
                const int pt = g * 64 + p * 16 + lane;
                s_s1[wv * 512 + pt] = s1[p];
                s_s2[wv * 512 + pt] = s2[p];
                s_k1[wv * 512 + pt] = k1[p];
            }
        }
    }
    __syncthreads();

    // ---- per-point 8-way union-top2 merge (thread = pt) ----
    {
        const int pt = tid;
        float m1 = s_s1[pt], m2 = s_s2[pt];
        int   mk = s_k1[pt];
        #pragma unroll
        for (int w = 1; w < 8; ++w) {
            const float a1 = s_s1[w * 512 + pt];
            const float a2 = s_s2[w * 512 + pt];
            const int   ak = s_k1[w * 512 + pt];
            // strict >: ascending slices = ascending codes -> first-occurrence
            if (a1 > m1) { m2 = fmaxf(m1, a2); m1 = a1; mk = ak; }
            else         { m2 = fmaxf(m2, a1); }
        }
        s_idx[pt] = mk;

        // near-tie: batched push to worklist (one atomic per wave)
        const bool flag = (m1 - m2) <= EPS_GAP;
        unsigned long long m = __ballot(flag);
        if (m) {
            int base = 0;
            if (lane == 0) base = atomicAdd(cnt, __popcll(m));
            base = __shfl(base, 0, 64);
            if (flag) {
                const int my = base + __popcll(m & ((1ull << lane) - 1));
                if (my < cap) {
                    list[my] = bb * TT + t0 + pt;
                } else {
                    // overflow fallback: exact fp64 scan (never in practice)
                    const float* xp = x + (size_t)bb * DD * TT + t0 + pt;
                    double bd = 1e300; int bk2 = 0;
                    for (int k = 0; k < KK; ++k) {
                        const float* wk = weight + (size_t)k * DD;
                        double a0 = 0.0;
                        for (int d = 0; d < DD; ++d) {
                            double e = (double)xp[(size_t)d * TT] - (double)wk[d];
                            a0 = fma(e, e, a0);
                        }
                        if (a0 < bd) { bd = a0; bk2 = k; }
                    }
                    s_idx[pt] = bk2;
                }
            }
        }
    }
    __syncthreads();

    // ---- epilogue: 512-pt tiles -> 2KB contiguous regions per (b,d) ----
    out[(size_t)BB * DD * TT + (size_t)bb * TT + t0 + tid] = (float)s_idx[tid];

    {
        const int kq = s_idx[tid];
        const float4* wr = (const float4*)(weight + (size_t)kq * DD);
        float* op = out + (size_t)bb * DD * TT + t0 + tid;
        #pragma unroll
        for (int jq = 0; jq < 16; ++jq) {
            float4 v = wr[jq];
            op[(size_t)(jq * 4 + 0) * TT] = v.x;
            op[(size_t)(jq * 4 + 1) * TT] = v.y;
            op[(size_t)(jq * 4 + 2) * TT] = v.z;
            op[(size_t)(jq * 4 + 3) * TT] = v.w;
        }
    }
}

// ---- fixup: flagged points, coalesced exact fp64 full scan ----
__global__ __launch_bounds__(256) void vq_fixup(
    const float* __restrict__ x, const float* __restrict__ w,
    const int* __restrict__ cnt, const int* __restrict__ list, int cap,
    float* __restrict__ out)
{
    __shared__ double sd[4];
    __shared__ int    sk[4];
    int n = *cnt; if (n > cap) n = cap;

    for (int i = blockIdx.x; i < n; i += gridDim.x) {
        const int g = list[i];
        const int b = g >> 12;             // TT = 4096
        const int t = g & (TT - 1);
        const float* xp = x + (size_t)b * DD * TT + t;

        const int quarter = threadIdx.x & 3;       // 16 d's each
        const int cbase   = threadIdx.x >> 2;      // 0..63

        double xq[16];
        #pragma unroll
        for (int j = 0; j < 16; ++j)
            xq[j] = (double)xp[(size_t)(quarter * 16 + j) * TT];

        double bd = 1e300; int bk = 0;
        for (int it = 0; it < 16; ++it) {
            const int code = cbase + (it << 6);
            const float4* wr = (const float4*)(w + (size_t)code * DD + quarter * 16);
            double a = 0.0;
            #pragma unroll
            for (int q4 = 0; q4 < 4; ++q4) {
                float4 v = wr[q4];
                double e0 = xq[q4 * 4 + 0] - (double)v.x;
                double e1 = xq[q4 * 4 + 1] - (double)v.y;
                double e2 = xq[q4 * 4 + 2] - (double)v.z;
                double e3 = xq[q4 * 4 + 3] - (double)v.w;
                a = fma(e0, e0, a); a = fma(e1, e1, a);
                a = fma(e2, e2, a); a = fma(e3, e3, a);
            }
            a += __shfl_xor(a, 1, 64);
            a += __shfl_xor(a, 2, 64);
            if (a < bd || (a == bd && code < bk)) { bd = a; bk = code; }
        }
        #pragma unroll
        for (int off = 4; off < 64; off <<= 1) {
            double od = __shfl_xor(bd, off, 64);
            int    ok = __shfl_xor(bk, off, 64);
            if (od < bd || (od == bd && ok < bk)) { bd = od; bk = ok; }
        }
        if ((threadIdx.x & 63) == 0) { sd[threadIdx.x >> 6] = bd; sk[threadIdx.x >> 6] = bk; }
        __syncthreads();
        double fb = sd[0]; int fk = sk[0];
        #pragma unroll
        for (int wvi = 1; wvi < 4; ++wvi)
            if (sd[wvi] < fb || (sd[wvi] == fb && sk[wvi] < fk)) { fb = sd[wvi]; fk = sk[wvi]; }

        if (threadIdx.x == 0)
            out[(size_t)BB * DD * TT + g] = (float)fk;
        if (threadIdx.x < 64)
            out[(size_t)b * DD * TT + (size_t)threadIdx.x * TT + t] = w[(size_t)fk * DD + threadIdx.x];
        __syncthreads();   // sd/sk reuse across iterations
    }
}

extern "C" void kernel_launch(void* const* d_in, const int* in_sizes, int n_in,
                              void* d_out, int out_size, void* d_ws, size_t ws_size,
                              hipStream_t stream) {
    const float* x      = (const float*)d_in[0];
    const float* weight = (const float*)d_in[1];
    float* out = (float*)d_out;

    float* bias     = (float*)d_ws;
    _Float16* rec   = (_Float16*)((char*)d_ws + REC_OFF);
    int* cnt        = (int*)((char*)d_ws + CNT_OFF);
    int* list       = (int*)((char*)d_ws + LIST_OFF);
    long long avail = (long long)ws_size - LIST_OFF;
    int cap = avail > 0 ? (int)(avail / 4) : 0;
    if (cap > BB * TT) cap = BB * TT;

    vq_prep<<<32, 256, 0, stream>>>(weight, bias, rec, cnt);
    vq_main<<<(BB * TT) / 512, 512, LDS_BYTES, stream>>>(x, weight, bias, rec, cnt, list, cap, out);
    vq_fixup<<<1024, 256, 0, stream>>>(x, weight, cnt, list, cap, out);
}

// Round 14
// 65.862 us; speedup vs baseline: 1.7012x; 1.4988x over previous
//
#include <hip/hip_runtime.h>

// VQ codebook assign: argmin_k ||x-w_k||^2 = argmax_k (x.w_k - 0.5||w_k||^2)
// Round 14: round-10 structure (LDS-resident fp16 codebook, proven 44us/no
// spill) with DOUBLE the TLP: 1024-thr blocks (16 waves), 32 pts/wave,
// 512 pts/block, grid 256 -> 4 waves/SIMD (was 2). Live state ~110 VGPR
// fits the 128-VGPR cap that 16-wave blocks require (rounds 11-13 proved
// the compiler pins 128 for >=8-wave blocks; this design needs no more).
// K-loop: 2-stage register prefetch of A-frags+bias from LDS, 8 MFMA +
// 16-score fmed3 top-2 per chunk. Exactness: fp16 single-pass + EPS=1/64
// (~5 sigma) + worklist + fp64 fixup kernel.
//
// ws: bias[1024]f32 @0 | rec fp16 @4096 (128KB) | cnt @135168 | list @135184

#define BB 32
#define DD 64
#define TT 4096
#define KK 1024
#define EPS_GAP 0.015625f

#define REC_OFF  4096
#define CNT_OFF  135168
#define LIST_OFF 135184

#define LDS_BYTES (131072 + 4096 + 2048)   // rec + bias + s_idx

typedef __attribute__((ext_vector_type(8))) _Float16 half8;
typedef __attribute__((ext_vector_type(4))) float f32x4;

// ---- prep: weight -> swizzled fp16 A-frag records + bias; reset cnt ----
// record r = kc*4 + ks*2 + c (0..127): lane l holds code kc*32+c*16+(l&15),
// d = ks*32+(l>>4)*8+e, 8 halves = 16B. 128 recs * 1KB = 128KB.
__global__ __launch_bounds__(256) void vq_prep(
    const float* __restrict__ w, float* __restrict__ bias,
    _Float16* __restrict__ rec, int* __restrict__ cnt)
{
    const int g    = blockIdx.x * 256 + threadIdx.x;   // 0..8191
    if (g == 0) *cnt = 0;
    const int lane = g & 63;
    const int r    = g >> 6;                           // record 0..127
    const int kc   = r >> 2, ks = (r >> 1) & 1, c = r & 1;
    const int code  = kc * 32 + c * 16 + (lane & 15);
    const int dbase = ks * 32 + (lane >> 4) * 8;

    const float* src = w + (size_t)code * DD + dbase;
    float4 f0 = *(const float4*)src;
    float4 f1 = *(const float4*)(src + 4);
    half8 hv;
    hv[0] = (_Float16)f0.x; hv[1] = (_Float16)f0.y;
    hv[2] = (_Float16)f0.z; hv[3] = (_Float16)f0.w;
    hv[4] = (_Float16)f1.x; hv[5] = (_Float16)f1.y;
    hv[6] = (_Float16)f1.z; hv[7] = (_Float16)f1.w;
    *(half8*)(rec + (size_t)r * 512 + lane * 8) = hv;

    if (g < KK) {
        const float4* wp = (const float4*)(w + (size_t)g * DD);
        float s = 0.f;
        #pragma unroll
        for (int j = 0; j < 16; ++j) {
            float4 v = wp[j];
            s += v.x * v.x + v.y * v.y + v.z * v.z + v.w * v.w;
        }
        bias[g] = -0.5f * s;
    }
}

// ---- main: 16 waves x 32 pts (full K each); 512 pts/block, 256 blocks ----
__global__ __launch_bounds__(1024, 1) void vq_main(
    const float* __restrict__ x,
    const float* __restrict__ weight,
    const float* __restrict__ bias,
    const _Float16* __restrict__ rec,
    int* __restrict__ cnt, int* __restrict__ list, int cap,
    float* __restrict__ out)
{
    extern __shared__ char smem[];
    _Float16* l_rec  = (_Float16*)smem;                    // [128 rec][512 halves]
    float*    l_bias = (float*)(smem + 131072);            // [1024]
    int*      s_idx  = (int*)(smem + 131072 + 4096);       // [512]

    const int tid  = threadIdx.x;                  // 0..1023
    const int lane = tid & 63;
    const int wv   = tid >> 6;                     // 0..15
    const int bb   = blockIdx.x >> 3;              // 8 tiles of 512 pts per batch
    const int t0   = (blockIdx.x & 7) << 9;
    const int col  = lane & 15, kg = lane >> 4;

    // ---- stage rec + bias into LDS (coalesced int4 copies) ----
    {
        const int4* src = (const int4*)rec;        // 8192 int4 = 128KB
        int4* dst = (int4*)l_rec;
        #pragma unroll
        for (int s = 0; s < 8; ++s)
            dst[s * 1024 + tid] = src[s * 1024 + tid];
        l_bias[tid] = bias[tid];                   // 1024 floats
    }

    // ---- x -> fp16 B-frags straight from global (overlaps staging wait) ----
    half8 Bf[2][2];                                // [pt-tile][kstep]
    {
        const float* xb = x + (size_t)bb * DD * TT + t0 + wv * 32 + col;
        #pragma unroll
        for (int p = 0; p < 2; ++p)
            #pragma unroll
            for (int ks = 0; ks < 2; ++ks) {
                half8 hv;
                #pragma unroll
                for (int e = 0; e < 8; ++e)
                    hv[e] = (_Float16)xb[(size_t)(ks * 32 + kg * 8 + e) * TT + p * 16];
                Bf[p][ks] = hv;
            }
    }
    __syncthreads();

    float s1[2] = {-1e30f, -1e30f};
    float s2[2] = {-1e30f, -1e30f};
    int   k1[2] = {0, 0};

    // loadA: A-frags + bias C-in from LDS (ds_read_b128, conflict-free)
    auto loadA = [&](int kc, half8 (*A)[2], f32x4* Bv) {
        #pragma unroll
        for (int ks = 0; ks < 2; ++ks)
            #pragma unroll
            for (int c = 0; c < 2; ++c)
                A[ks][c] = *(const half8*)(l_rec + (kc * 4 + ks * 2 + c) * 512 + lane * 8);
        #pragma unroll
        for (int c = 0; c < 2; ++c)
            Bv[c] = *(const f32x4*)(l_bias + kc * 32 + c * 16 + kg * 4);
    };
    auto compute = [&](int kc, half8 (*A)[2], f32x4* Bv) {
        f32x4 acc[2][2];                           // [c-tile][pt-tile]
        #pragma unroll
        for (int c = 0; c < 2; ++c)
            #pragma unroll
            for (int p = 0; p < 2; ++p) {
                acc[c][p] = __builtin_amdgcn_mfma_f32_16x16x32_f16(A[0][c], Bf[p][0], Bv[c], 0, 0, 0);
                acc[c][p] = __builtin_amdgcn_mfma_f32_16x16x32_f16(A[1][c], Bf[p][1], acc[c][p], 0, 0, 0);
            }
        #pragma unroll
        for (int p = 0; p < 2; ++p)
            #pragma unroll
            for (int c = 0; c < 2; ++c)
                #pragma unroll
                for (int r = 0; r < 4; ++r) {
                    const float s = acc[c][p][r];
                    const int code = kc * 32 + c * 16 + kg * 4 + r;
                    // s2<=s1 invariant -> med3(s,s1,s2) == new second-best
                    const float ns2 = __builtin_amdgcn_fmed3f(s, s1[p], s2[p]);
                    if (s > s1[p]) { k1[p] = code; s1[p] = s; }
                    s2[p] = ns2;
                }
    };

    // K loop: 32 chunks, 2-stage register prefetch from LDS
    half8 A0[2][2], A1[2][2];
    f32x4 Bv0[2], Bv1[2];
    loadA(0, A0, Bv0);
    for (int kc = 0; kc < 32; kc += 2) {
        loadA(kc + 1, A1, Bv1);
        compute(kc, A0, Bv0);
        if (kc + 2 < 32) loadA(kc + 2, A0, Bv0);
        compute(kc + 1, A1, Bv1);
    }

    // intra-wave merge: lanes l, l^16, l^32, l^48 share a point
    #pragma unroll
    for (int p = 0; p < 2; ++p) {
        #pragma unroll
        for (int off = 16; off < 64; off <<= 1) {
            float o1 = __shfl_xor(s1[p], off, 64);
            float o2 = __shfl_xor(s2[p], off, 64);
            int   ok = __shfl_xor(k1[p], off, 64);
            bool takeo = (o1 > s1[p]) || (o1 == s1[p] && ok < k1[p]);
            float ns2 = fmaxf(fminf(s1[p], o1), fmaxf(s2[p], o2));
            if (takeo) { s1[p] = o1; k1[p] = ok; }
            s2[p] = ns2;
        }

        // near-tie: batched push to worklist (one atomic per wave per p)
        const bool flag = (lane < 16) && ((s1[p] - s2[p]) <= EPS_GAP);
        unsigned long long m = __ballot(flag);
        if (m) {
            int base = 0;
            if (lane == 0) base = atomicAdd(cnt, __popcll(m));
            base = __shfl(base, 0, 64);
            if (flag) {
                const int my = base + __popcll(m & ((1ull << lane) - 1));
                if (my < cap) {
                    list[my] = bb * TT + t0 + wv * 32 + p * 16 + lane;
                } else {
                    // overflow fallback: exact per-lane fp64 scan (never in practice)
                    const float* xp = x + (size_t)bb * DD * TT + t0 + wv * 32 + p * 16 + lane;
                    double bd = 1e300; int bk2 = 0;
                    for (int k = 0; k < KK; ++k) {
                        const float* wk = weight + (size_t)k * DD;
                        double a0 = 0.0;
                        for (int d = 0; d < DD; ++d) {
                            double e = (double)xp[(size_t)d * TT] - (double)wk[d];
                            a0 = fma(e, e, a0);
                        }
                        if (a0 < bd) { bd = a0; bk2 = k; }
                    }
                    k1[p] = bk2;
                }
            }
        }
        if (lane < 16) s_idx[wv * 32 + p * 16 + lane] = k1[p];
    }
    __syncthreads();

    // ---- epilogue: 512-pt tiles -> 2KB contiguous regions per (b,d) ----
    // indices (as float): 512 threads, 2KB contiguous
    if (tid < 512)
        out[(size_t)BB * DD * TT + (size_t)bb * TT + t0 + tid] = (float)s_idx[tid];

    // quantized: thread = (pt = tid&511, dh = tid>>9 covering 32 d's);
    // consecutive lanes = consecutive points -> 256B/store, 2KB per (b,d)
    {
        const int pt = tid & 511;
        const int dh = tid >> 9;
        const int kq = s_idx[pt];
        const float4* wr = (const float4*)(weight + (size_t)kq * DD + dh * 32);
        float* op = out + ((size_t)bb * DD + dh * 32) * TT + t0 + pt;
        #pragma unroll
        for (int jq = 0; jq < 8; ++jq) {
            float4 v = wr[jq];
            op[(size_t)(jq * 4 + 0) * TT] = v.x;
            op[(size_t)(jq * 4 + 1) * TT] = v.y;
            op[(size_t)(jq * 4 + 2) * TT] = v.z;
            op[(size_t)(jq * 4 + 3) * TT] = v.w;
        }
    }
}

// ---- fixup: flagged points, coalesced exact fp64 full scan ----
__global__ __launch_bounds__(256) void vq_fixup(
    const float* __restrict__ x, const float* __restrict__ w,
    const int* __restrict__ cnt, const int* __restrict__ list, int cap,
    float* __restrict__ out)
{
    __shared__ double sd[4];
    __shared__ int    sk[4];
    int n = *cnt; if (n > cap) n = cap;

    for (int i = blockIdx.x; i < n; i += gridDim.x) {
        const int g = list[i];
        const int b = g >> 12;             // TT = 4096
        const int t = g & (TT - 1);
        const float* xp = x + (size_t)b * DD * TT + t;

        const int quarter = threadIdx.x & 3;       // 16 d's each
        const int cbase   = threadIdx.x >> 2;      // 0..63

        double xq[16];
        #pragma unroll
        for (int j = 0; j < 16; ++j)
            xq[j] = (double)xp[(size_t)(quarter * 16 + j) * TT];

        double bd = 1e300; int bk = 0;
        for (int it = 0; it < 16; ++it) {
            const int code = cbase + (it << 6);
            const float4* wr = (const float4*)(w + (size_t)code * DD + quarter * 16);
            double a = 0.0;
            #pragma unroll
            for (int q4 = 0; q4 < 4; ++q4) {
                float4 v = wr[q4];
                double e0 = xq[q4 * 4 + 0] - (double)v.x;
                double e1 = xq[q4 * 4 + 1] - (double)v.y;
                double e2 = xq[q4 * 4 + 2] - (double)v.z;
                double e3 = xq[q4 * 4 + 3] - (double)v.w;
                a = fma(e0, e0, a); a = fma(e1, e1, a);
                a = fma(e2, e2, a); a = fma(e3, e3, a);
            }
            a += __shfl_xor(a, 1, 64);
            a += __shfl_xor(a, 2, 64);
            if (a < bd || (a == bd && code < bk)) { bd = a; bk = code; }
        }
        #pragma unroll
        for (int off = 4; off < 64; off <<= 1) {
            double od = __shfl_xor(bd, off, 64);
            int    ok = __shfl_xor(bk, off, 64);
            if (od < bd || (od == bd && ok < bk)) { bd = od; bk = ok; }
        }
        if ((threadIdx.x & 63) == 0) { sd[threadIdx.x >> 6] = bd; sk[threadIdx.x >> 6] = bk; }
        __syncthreads();
        double fb = sd[0]; int fk = sk[0];
        #pragma unroll
        for (int wvi = 1; wvi < 4; ++wvi)
            if (sd[wvi] < fb || (sd[wvi] == fb && sk[wvi] < fk)) { fb = sd[wvi]; fk = sk[wvi]; }

        if (threadIdx.x == 0)
            out[(size_t)BB * DD * TT + g] = (float)fk;
        if (threadIdx.x < 64)
            out[(size_t)b * DD * TT + (size_t)threadIdx.x * TT + t] = w[(size_t)fk * DD + threadIdx.x];
        __syncthreads();   // sd/sk reuse across iterations
    }
}

extern "C" void kernel_launch(void* const* d_in, const int* in_sizes, int n_in,
                              void* d_out, int out_size, void* d_ws, size_t ws_size,
                              hipStream_t stream) {
    const float* x      = (const float*)d_in[0];
    const float* weight = (const float*)d_in[1];
    float* out = (float*)d_out;

    float* bias     = (float*)d_ws;
    _Float16* rec   = (_Float16*)((char*)d_ws + REC_OFF);
    int* cnt        = (int*)((char*)d_ws + CNT_OFF);
    int* list       = (int*)((char*)d_ws + LIST_OFF);
    long long avail = (long long)ws_size - LIST_OFF;
    int cap = avail > 0 ? (int)(avail / 4) : 0;
    if (cap > BB * TT) cap = BB * TT;

    vq_prep<<<32, 256, 0, stream>>>(weight, bias, rec, cnt);
    vq_main<<<(BB * TT) / 512, 1024, LDS_BYTES, stream>>>(x, weight, bias, rec, cnt, list, cap, out);
    vq_fixup<<<1024, 256, 0, stream>>>(x, weight, cnt, list, cap, out);
}